// Round 2
// baseline (1497.331 us; speedup 1.0000x reference)
//
#include <hip/hip_runtime.h>
#include <math.h>

// Problem constants (fixed by setup_inputs)
#define NN 100000
#define EE 1600000
#define FF 128
#define DD 64
#define GG 512

// ---------------- degree / norm ----------------
__global__ void init_deg(float* deg) {
    int i = blockIdx.x * 256 + threadIdx.x;
    if (i < NN) deg[i] = 1.0f;   // self loop
}

__global__ void edge_deg(const int* __restrict__ dst, float* deg) {
    int e = blockIdx.x * 256 + threadIdx.x;
    if (e < EE) atomicAdd(&deg[dst[e]], 1.0f);
}

__global__ void make_dinv(float* deg) {
    int i = blockIdx.x * 256 + threadIdx.x;
    if (i < NN) deg[i] = rsqrtf(deg[i]);   // deg >= 1 always (self loop)
}

// ---------------- CSR build ----------------
// Exclusive scan of indeg = (int)deg - 1 over N elements, single block.
__global__ void scan_indeg(const float* __restrict__ deg, int* __restrict__ row_ptr,
                           int* __restrict__ cursor) {
    __shared__ int tmp[1024];
    __shared__ int carry;
    int tid = threadIdx.x;
    if (tid == 0) carry = 0;
    __syncthreads();
    for (int base = 0; base < NN; base += 1024) {
        int idx = base + tid;
        int v = (idx < NN) ? ((int)deg[idx] - 1) : 0;
        tmp[tid] = v;
        __syncthreads();
        #pragma unroll
        for (int off = 1; off < 1024; off <<= 1) {
            int t = (tid >= off) ? tmp[tid - off] : 0;
            __syncthreads();
            tmp[tid] += t;
            __syncthreads();
        }
        int excl = carry + tmp[tid] - v;
        if (idx < NN) { row_ptr[idx] = excl; cursor[idx] = excl; }
        __syncthreads();
        if (tid == 1023) carry += tmp[1023];
        __syncthreads();
    }
    if (tid == 0) row_ptr[NN] = carry;   // == EE
}

__global__ void fill_csr(const int* __restrict__ src, const int* __restrict__ dst,
                         int* __restrict__ cursor, int* __restrict__ col) {
    int e = blockIdx.x * 256 + threadIdx.x;
    if (e < EE) {
        int u = src[e], v = dst[e];
        int pos = atomicAdd(&cursor[v], 1);
        col[pos] = u;
    }
}

// ---------------- dense transform: T = X @ W ----------------
template <int K>
__global__ __launch_bounds__(256) void gemm_k(const float* __restrict__ X,
                                              const float* __restrict__ W,
                                              float* __restrict__ T) {
    __shared__ float sW[K * 64];
    __shared__ float sX[4 * K];
    int tid = threadIdx.x;
    int row0 = blockIdx.x * 4;
    for (int i = tid; i < K * 64; i += 256) sW[i] = W[i];
    for (int i = tid; i < 4 * K; i += 256) sX[i] = X[(size_t)row0 * K + i];
    __syncthreads();
    int rg = tid >> 6, c = tid & 63;
    const float* xr = &sX[rg * K];
    float acc = 0.f;
    #pragma unroll
    for (int k = 0; k < K; ++k) acc = fmaf(xr[k], sW[k * 64 + c], acc);
    T[(size_t)(row0 + rg) * 64 + c] = acc;
}

// ---------------- aggregation: H[v] = tanh(b + sum_{u->v} T[u]*dinv[u]*dinv[v] + T[v]*dinv[v]^2) ----------------
__global__ __launch_bounds__(256) void agg_k(const float* __restrict__ T,
                                             const float* __restrict__ dinv,
                                             const int* __restrict__ row_ptr,
                                             const int* __restrict__ col,
                                             const float* __restrict__ bias,
                                             float* __restrict__ H) {
    int node = blockIdx.x * 4 + (threadIdx.x >> 6);
    int lane = threadIdx.x & 63;
    float dv = dinv[node];
    float acc = bias[lane] + T[(size_t)node * 64 + lane] * (dv * dv);
    int beg = row_ptr[node], end = row_ptr[node + 1];
    for (int j = beg; j < end; ++j) {
        int u = col[j];
        acc = fmaf(T[(size_t)u * 64 + lane], dinv[u] * dv, acc);
    }
    H[(size_t)node * 64 + lane] = tanhf(acc);
}

// ---------------- pooling ----------------
__global__ void hist_batch(const int* __restrict__ batch, int* counts) {
    int i = blockIdx.x * 256 + threadIdx.x;
    if (i < NN) atomicAdd(&counts[batch[i]], 1);
}

__global__ void scan_counts(const int* __restrict__ counts, int* __restrict__ gstart) {
    __shared__ int tmp[GG];
    int tid = threadIdx.x;
    int v = counts[tid];
    tmp[tid] = v;
    __syncthreads();
    #pragma unroll
    for (int off = 1; off < GG; off <<= 1) {
        int t = (tid >= off) ? tmp[tid - off] : 0;
        __syncthreads();
        tmp[tid] += t;
        __syncthreads();
    }
    gstart[tid] = tmp[tid] - v;           // exclusive
    if (tid == GG - 1) gstart[GG] = tmp[GG - 1];   // == NN
}

__global__ void pool_k(const float* __restrict__ H, const int* __restrict__ gstart,
                       float* __restrict__ hidden) {
    int g = blockIdx.x, lane = threadIdx.x;   // 64 threads
    int beg = gstart[g], end = gstart[g + 1];
    float mx = -3.402823466e38f, sm = 0.f;
    for (int i = beg; i < end; ++i) {
        float v = H[(size_t)i * 64 + lane];
        mx = fmaxf(mx, v);
        sm += v;
    }
    int cnt = end - beg;
    hidden[g * 128 + lane]      = (cnt > 0) ? mx : 0.f;
    hidden[g * 128 + 64 + lane] = sm / fmaxf((float)cnt, 1.f);
}

__global__ void head_k(const float* __restrict__ hidden, const float* __restrict__ Wout,
                       const float* __restrict__ bout, float* __restrict__ out) {
    int g = blockIdx.x, lane = threadIdx.x;   // 64 threads
    float v = hidden[g * 128 + lane] * Wout[lane]
            + hidden[g * 128 + 64 + lane] * Wout[64 + lane];
    #pragma unroll
    for (int off = 32; off; off >>= 1) v += __shfl_down(v, off);
    if (lane == 0) out[g] = 1.f / (1.f + expf(-(v + bout[0])));
}

// ---------------- launch ----------------
extern "C" void kernel_launch(void* const* d_in, const int* in_sizes, int n_in,
                              void* d_out, int out_size, void* d_ws, size_t ws_size,
                              hipStream_t stream) {
    const float* x     = (const float*)d_in[0];
    const int*   ei    = (const int*)d_in[1];
    const int*   src   = ei;
    const int*   dst   = ei + EE;
    const int*   batch = (const int*)d_in[2];
    const float* W0 = (const float*)d_in[4];  const float* b0 = (const float*)d_in[5];
    const float* W1 = (const float*)d_in[6];  const float* b1 = (const float*)d_in[7];
    const float* W2 = (const float*)d_in[8];  const float* b2 = (const float*)d_in[9];
    const float* W3 = (const float*)d_in[10]; const float* b3 = (const float*)d_in[11];
    const float* Wout = (const float*)d_in[12]; const float* bout = (const float*)d_in[13];

    float* out    = (float*)d_out;
    float* hidden = out + GG;     // [G,128] portion of d_out

    char*  w = (char*)d_ws;
    size_t off = 0;
    auto alloc = [&](size_t bytes) -> char* {
        char* p = w + off;
        off = (off + bytes + 255) & ~(size_t)255;
        return p;
    };
    float* deg     = (float*)alloc(NN * 4);            // becomes dinv in place
    int*   row_ptr = (int*)  alloc((NN + 1) * 4);
    int*   cursor  = (int*)  alloc(NN * 4);
    int*   col     = (int*)  alloc((size_t)EE * 4);
    float* T       = (float*)alloc((size_t)NN * 64 * 4);
    float* A       = (float*)alloc((size_t)NN * 64 * 4);
    int*   counts  = (int*)  alloc(GG * 4);
    int*   gstart  = (int*)  alloc((GG + 1) * 4);
    (void)ws_size; (void)in_sizes; (void)n_in; (void)out_size;

    // degree + symmetric norm
    init_deg<<<(NN + 255) / 256, 256, 0, stream>>>(deg);
    edge_deg<<<(EE + 255) / 256, 256, 0, stream>>>(dst, deg);
    // CSR build (reads deg BEFORE it becomes dinv)
    scan_indeg<<<1, 1024, 0, stream>>>(deg, row_ptr, cursor);
    make_dinv<<<(NN + 255) / 256, 256, 0, stream>>>(deg);
    fill_csr<<<(EE + 255) / 256, 256, 0, stream>>>(src, dst, cursor, col);

    // pooling prep (independent of layers)
    hipMemsetAsync(counts, 0, GG * sizeof(int), stream);
    hist_batch<<<(NN + 255) / 256, 256, 0, stream>>>(batch, counts);
    scan_counts<<<1, GG, 0, stream>>>(counts, gstart);

    // 4 GCN layers (transform -> aggregate+bias+tanh)
    gemm_k<FF><<<NN / 4, 256, 0, stream>>>(x, W0, T);
    agg_k<<<NN / 4, 256, 0, stream>>>(T, deg, row_ptr, col, b0, A);
    gemm_k<DD><<<NN / 4, 256, 0, stream>>>(A, W1, T);
    agg_k<<<NN / 4, 256, 0, stream>>>(T, deg, row_ptr, col, b1, A);
    gemm_k<DD><<<NN / 4, 256, 0, stream>>>(A, W2, T);
    agg_k<<<NN / 4, 256, 0, stream>>>(T, deg, row_ptr, col, b2, A);
    gemm_k<DD><<<NN / 4, 256, 0, stream>>>(A, W3, T);
    agg_k<<<NN / 4, 256, 0, stream>>>(T, deg, row_ptr, col, b3, A);

    // pooling + head
    pool_k<<<GG, 64, 0, stream>>>(A, gstart, hidden);
    head_k<<<GG, 64, 0, stream>>>(hidden, Wout, bout, out);
}

// Round 5
// 857.803 us; speedup vs baseline: 1.7455x; 1.7455x over previous
//
#include <hip/hip_runtime.h>
#include <math.h>
#include <float.h>

// Problem constants (fixed by setup_inputs)
#define NN 100000
#define EE 1600000
#define FF 128
#define DD 64
#define GG 512
#define NBLK 98   // ceil(NN/1024)

// ---------------- degree ----------------
__global__ void init_deg(int* degi) {
    int i = blockIdx.x * 256 + threadIdx.x;
    if (i < NN) degi[i] = 1;   // self loop
}

__global__ void edge_deg(const int* __restrict__ dst, int* degi) {
    int e = blockIdx.x * 256 + threadIdx.x;
    if (e < EE) atomicAdd(&degi[dst[e]], 1);
}

__global__ void make_dinv(const int* __restrict__ degi, float* __restrict__ dinv) {
    int i = blockIdx.x * 256 + threadIdx.x;
    if (i < NN) dinv[i] = rsqrtf((float)degi[i]);   // deg >= 1 always
}

// ---------------- hierarchical exclusive scan of indeg = degi-1 ----------------
__global__ void scan_partial(const int* __restrict__ degi, int* __restrict__ partial) {
    __shared__ int red[1024];
    int tid = threadIdx.x;
    int idx = blockIdx.x * 1024 + tid;
    red[tid] = (idx < NN) ? degi[idx] - 1 : 0;
    __syncthreads();
    #pragma unroll
    for (int off = 512; off; off >>= 1) {
        if (tid < off) red[tid] += red[tid + off];
        __syncthreads();
    }
    if (tid == 0) partial[blockIdx.x] = red[0];
}

__global__ void scan_offsets(int* __restrict__ partial, int* __restrict__ row_ptr) {
    __shared__ int tmp[128];
    int tid = threadIdx.x;   // 128 threads
    int v = (tid < NBLK) ? partial[tid] : 0;
    tmp[tid] = v;
    __syncthreads();
    #pragma unroll
    for (int off = 1; off < 128; off <<= 1) {
        int t = (tid >= off) ? tmp[tid - off] : 0;
        __syncthreads();
        tmp[tid] += t;
        __syncthreads();
    }
    if (tid < NBLK) partial[tid] = tmp[tid] - v;     // exclusive block offsets
    if (tid == NBLK - 1) row_ptr[NN] = tmp[tid];     // total == EE
}

__global__ void scan_final(const int* __restrict__ degi, const int* __restrict__ partial,
                           int* __restrict__ row_ptr, int* __restrict__ cursor) {
    __shared__ int tmp[1024];
    int tid = threadIdx.x;
    int idx = blockIdx.x * 1024 + tid;
    int v = (idx < NN) ? degi[idx] - 1 : 0;
    tmp[tid] = v;
    __syncthreads();
    #pragma unroll
    for (int off = 1; off < 1024; off <<= 1) {
        int t = (tid >= off) ? tmp[tid - off] : 0;
        __syncthreads();
        tmp[tid] += t;
        __syncthreads();
    }
    int excl = partial[blockIdx.x] + tmp[tid] - v;
    if (idx < NN) { row_ptr[idx] = excl; cursor[idx] = excl; }
}

// ---------------- CSR fill with precomputed symmetric weights ----------------
__global__ void fill_csr(const int* __restrict__ src, const int* __restrict__ dst,
                         const float* __restrict__ dinv,
                         int* __restrict__ cursor, int2* __restrict__ cw) {
    int e = blockIdx.x * 256 + threadIdx.x;
    if (e < EE) {
        int u = src[e], v = dst[e];
        int pos = atomicAdd(&cursor[v], 1);
        float w = dinv[u] * dinv[v];
        cw[pos] = make_int2(u, __float_as_int(w));
    }
}

// ---------------- dense transform: T = X @ W  (16 rows / block) ----------------
template <int K>
__global__ __launch_bounds__(256) void gemm_k(const float* __restrict__ X,
                                              const float* __restrict__ W,
                                              float* __restrict__ T) {
    __shared__ float sW[K * 64];
    __shared__ float sX[16 * K];
    int tid = threadIdx.x;
    size_t row0 = (size_t)blockIdx.x * 16;
    for (int i = tid; i < K * 64; i += 256) sW[i] = W[i];
    for (int i = tid; i < 16 * K; i += 256) sX[i] = X[row0 * K + i];
    __syncthreads();
    int rg = tid >> 6, c = tid & 63;
    #pragma unroll
    for (int r = rg; r < 16; r += 4) {
        const float* xr = &sX[r * K];
        float acc = 0.f;
        #pragma unroll
        for (int k = 0; k < K; ++k) acc = fmaf(xr[k], sW[k * 64 + c], acc);
        T[(row0 + r) * 64 + c] = acc;
    }
}

// ---------------- aggregation ----------------
// One wave per node. 4 groups of 16 lanes; group g processes edge j=beg+i*4+g,
// each lane loads float4 (16 B) of the 256 B source row -> 4 edges in flight.
__global__ __launch_bounds__(256) void agg_k(const float4* __restrict__ T4,
                                             const float* __restrict__ dinv,
                                             const int* __restrict__ row_ptr,
                                             const int2* __restrict__ cw,
                                             const float4* __restrict__ bias4,
                                             float4* __restrict__ H4) {
    int node = blockIdx.x * 4 + (threadIdx.x >> 6);
    int lane = threadIdx.x & 63;
    int grp  = lane >> 4;      // 0..3 : which edge of the quad
    int fl   = lane & 15;      // which float4 of the row
    int beg = row_ptr[node], end = row_ptr[node + 1];
    float4 acc = make_float4(0.f, 0.f, 0.f, 0.f);
    for (int j = beg + grp; j < end; j += 4) {
        int2 c = cw[j];
        float w = __int_as_float(c.y);
        float4 t = T4[(size_t)c.x * 16 + fl];
        acc.x = fmaf(t.x, w, acc.x);
        acc.y = fmaf(t.y, w, acc.y);
        acc.z = fmaf(t.z, w, acc.z);
        acc.w = fmaf(t.w, w, acc.w);
    }
    // butterfly-sum the 4 groups (lanes xor 16, 32)
    #pragma unroll
    for (int m = 16; m <= 32; m <<= 1) {
        acc.x += __shfl_xor(acc.x, m);
        acc.y += __shfl_xor(acc.y, m);
        acc.z += __shfl_xor(acc.z, m);
        acc.w += __shfl_xor(acc.w, m);
    }
    if (grp == 0) {   // lanes 0..15 write the 64-float row as 16 x float4
        float dv = dinv[node];
        float s = dv * dv;
        float4 t = T4[(size_t)node * 16 + fl];
        float4 b = bias4[fl];
        float4 o;
        o.x = tanhf(acc.x + t.x * s + b.x);
        o.y = tanhf(acc.y + t.y * s + b.y);
        o.z = tanhf(acc.z + t.z * s + b.z);
        o.w = tanhf(acc.w + t.w * s + b.w);
        H4[(size_t)node * 16 + fl] = o;
    }
}

// ---------------- pooling ----------------
__global__ void hist_batch(const int* __restrict__ batch, int* counts) {
    int i = blockIdx.x * 256 + threadIdx.x;
    if (i < NN) atomicAdd(&counts[batch[i]], 1);
}

__global__ void scan_counts(const int* __restrict__ counts, int* __restrict__ gstart) {
    __shared__ int tmp[GG];
    int tid = threadIdx.x;
    int v = counts[tid];
    tmp[tid] = v;
    __syncthreads();
    #pragma unroll
    for (int off = 1; off < GG; off <<= 1) {
        int t = (tid >= off) ? tmp[tid - off] : 0;
        __syncthreads();
        tmp[tid] += t;
        __syncthreads();
    }
    gstart[tid] = tmp[tid] - v;                    // exclusive
    if (tid == GG - 1) gstart[GG] = tmp[GG - 1];   // == NN
}

__global__ __launch_bounds__(256) void pool_k(const float* __restrict__ H,
                                              const int* __restrict__ gstart,
                                              float* __restrict__ hidden) {
    __shared__ float smax[4][64], ssum[4][64];
    int g = blockIdx.x;
    int wave = threadIdx.x >> 6, lane = threadIdx.x & 63;
    int beg = gstart[g], end = gstart[g + 1];
    float mx = -FLT_MAX, sm = 0.f;
    for (int i = beg + wave; i < end; i += 4) {
        float v = H[(size_t)i * 64 + lane];
        mx = fmaxf(mx, v);
        sm += v;
    }
    smax[wave][lane] = mx; ssum[wave][lane] = sm;
    __syncthreads();
    if (wave == 0) {
        mx = fmaxf(fmaxf(smax[0][lane], smax[1][lane]), fmaxf(smax[2][lane], smax[3][lane]));
        sm = ssum[0][lane] + ssum[1][lane] + ssum[2][lane] + ssum[3][lane];
        int cnt = end - beg;
        hidden[g * 128 + lane]      = (cnt > 0) ? mx : 0.f;
        hidden[g * 128 + 64 + lane] = sm / fmaxf((float)cnt, 1.f);
    }
}

__global__ void head_k(const float* __restrict__ hidden, const float* __restrict__ Wout,
                       const float* __restrict__ bout, float* __restrict__ out) {
    int g = blockIdx.x, lane = threadIdx.x;   // 64 threads
    float v = hidden[g * 128 + lane] * Wout[lane]
            + hidden[g * 128 + 64 + lane] * Wout[64 + lane];
    #pragma unroll
    for (int off = 32; off; off >>= 1) v += __shfl_down(v, off);
    if (lane == 0) out[g] = 1.f / (1.f + expf(-(v + bout[0])));
}

// ---------------- launch ----------------
extern "C" void kernel_launch(void* const* d_in, const int* in_sizes, int n_in,
                              void* d_out, int out_size, void* d_ws, size_t ws_size,
                              hipStream_t stream) {
    const float* x     = (const float*)d_in[0];
    const int*   ei    = (const int*)d_in[1];
    const int*   src   = ei;
    const int*   dst   = ei + EE;
    const int*   batch = (const int*)d_in[2];
    const float* W0 = (const float*)d_in[4];  const float* b0 = (const float*)d_in[5];
    const float* W1 = (const float*)d_in[6];  const float* b1 = (const float*)d_in[7];
    const float* W2 = (const float*)d_in[8];  const float* b2 = (const float*)d_in[9];
    const float* W3 = (const float*)d_in[10]; const float* b3 = (const float*)d_in[11];
    const float* Wout = (const float*)d_in[12]; const float* bout = (const float*)d_in[13];

    float* out    = (float*)d_out;
    float* hidden = out + GG;     // [G,128] portion of d_out

    char*  w = (char*)d_ws;
    size_t off = 0;
    auto alloc = [&](size_t bytes) -> char* {
        char* p = w + off;
        off = (off + bytes + 255) & ~(size_t)255;
        return p;
    };
    int*   degi    = (int*)  alloc(NN * 4);
    float* dinv    = (float*)alloc(NN * 4);
    int*   row_ptr = (int*)  alloc((NN + 1) * 4);
    int*   cursor  = (int*)  alloc(NN * 4);
    int*   partial = (int*)  alloc(NBLK * 4);
    int2*  cw      = (int2*) alloc((size_t)EE * 8);
    float* T       = (float*)alloc((size_t)NN * 64 * 4);
    float* A       = (float*)alloc((size_t)NN * 64 * 4);
    int*   counts  = (int*)  alloc(GG * 4);
    int*   gstart  = (int*)  alloc((GG + 1) * 4);
    (void)ws_size; (void)in_sizes; (void)n_in; (void)out_size;

    // degree + CSR offsets (hierarchical scan)
    init_deg<<<(NN + 255) / 256, 256, 0, stream>>>(degi);
    edge_deg<<<(EE + 255) / 256, 256, 0, stream>>>(dst, degi);
    scan_partial<<<NBLK, 1024, 0, stream>>>(degi, partial);
    scan_offsets<<<1, 128, 0, stream>>>(partial, row_ptr);
    scan_final<<<NBLK, 1024, 0, stream>>>(degi, partial, row_ptr, cursor);
    make_dinv<<<(NN + 255) / 256, 256, 0, stream>>>(degi, dinv);
    fill_csr<<<(EE + 255) / 256, 256, 0, stream>>>(src, dst, dinv, cursor, cw);

    // pooling prep
    hipMemsetAsync(counts, 0, GG * sizeof(int), stream);
    hist_batch<<<(NN + 255) / 256, 256, 0, stream>>>(batch, counts);
    scan_counts<<<1, GG, 0, stream>>>(counts, gstart);

    // 4 GCN layers (transform -> aggregate+bias+tanh)
    const float4* bias4;
    gemm_k<FF><<<NN / 16, 256, 0, stream>>>(x, W0, T);
    bias4 = (const float4*)b0;
    agg_k<<<NN / 4, 256, 0, stream>>>((const float4*)T, dinv, row_ptr, cw, bias4, (float4*)A);
    gemm_k<DD><<<NN / 16, 256, 0, stream>>>(A, W1, T);
    bias4 = (const float4*)b1;
    agg_k<<<NN / 4, 256, 0, stream>>>((const float4*)T, dinv, row_ptr, cw, bias4, (float4*)A);
    gemm_k<DD><<<NN / 16, 256, 0, stream>>>(A, W2, T);
    bias4 = (const float4*)b2;
    agg_k<<<NN / 4, 256, 0, stream>>>((const float4*)T, dinv, row_ptr, cw, bias4, (float4*)A);
    gemm_k<DD><<<NN / 16, 256, 0, stream>>>(A, W3, T);
    bias4 = (const float4*)b3;
    agg_k<<<NN / 4, 256, 0, stream>>>((const float4*)T, dinv, row_ptr, cw, bias4, (float4*)A);

    // pooling + head
    pool_k<<<GG, 256, 0, stream>>>(A, gstart, hidden);
    head_k<<<GG, 64, 0, stream>>>(hidden, Wout, bout, out);
}

// Round 6
// 851.276 us; speedup vs baseline: 1.7589x; 1.0077x over previous
//
#include <hip/hip_runtime.h>
#include <math.h>
#include <float.h>

// Problem constants (fixed by setup_inputs)
#define NN 100000
#define EE 1600000
#define FF 128
#define DD 64
#define GG 512
#define NBLK 98   // ceil(NN/1024)

__device__ __forceinline__ unsigned short f2bf(float f) {
    unsigned u = __float_as_uint(f);
    u = (u + 0x7fff + ((u >> 16) & 1)) >> 16;   // round-to-nearest-even
    return (unsigned short)u;
}
__device__ __forceinline__ float bflo(unsigned u) { return __uint_as_float(u << 16); }
__device__ __forceinline__ float bfhi(unsigned u) { return __uint_as_float(u & 0xffff0000u); }

// ---------------- degree ----------------
__global__ void init_deg(int* degi) {
    int i = blockIdx.x * 256 + threadIdx.x;
    if (i < NN) degi[i] = 1;   // self loop
}

__global__ void edge_deg(const int* __restrict__ dst, int* degi) {
    int e = blockIdx.x * 256 + threadIdx.x;
    if (e < EE) atomicAdd(&degi[dst[e]], 1);
}

__global__ void make_dinv(const int* __restrict__ degi, float* __restrict__ dinv) {
    int i = blockIdx.x * 256 + threadIdx.x;
    if (i < NN) dinv[i] = rsqrtf((float)degi[i]);   // deg >= 1 always
}

// ---------------- hierarchical exclusive scan of indeg = degi-1 ----------------
__global__ void scan_partial(const int* __restrict__ degi, int* __restrict__ partial) {
    __shared__ int red[1024];
    int tid = threadIdx.x;
    int idx = blockIdx.x * 1024 + tid;
    red[tid] = (idx < NN) ? degi[idx] - 1 : 0;
    __syncthreads();
    #pragma unroll
    for (int off = 512; off; off >>= 1) {
        if (tid < off) red[tid] += red[tid + off];
        __syncthreads();
    }
    if (tid == 0) partial[blockIdx.x] = red[0];
}

__global__ void scan_offsets(int* __restrict__ partial, int* __restrict__ row_ptr) {
    __shared__ int tmp[128];
    int tid = threadIdx.x;   // 128 threads
    int v = (tid < NBLK) ? partial[tid] : 0;
    tmp[tid] = v;
    __syncthreads();
    #pragma unroll
    for (int off = 1; off < 128; off <<= 1) {
        int t = (tid >= off) ? tmp[tid - off] : 0;
        __syncthreads();
        tmp[tid] += t;
        __syncthreads();
    }
    if (tid < NBLK) partial[tid] = tmp[tid] - v;     // exclusive block offsets
    if (tid == NBLK - 1) row_ptr[NN] = tmp[tid];     // total == EE
}

__global__ void scan_final(const int* __restrict__ degi, const int* __restrict__ partial,
                           int* __restrict__ row_ptr, int* __restrict__ cursor) {
    __shared__ int tmp[1024];
    int tid = threadIdx.x;
    int idx = blockIdx.x * 1024 + tid;
    int v = (idx < NN) ? degi[idx] - 1 : 0;
    tmp[tid] = v;
    __syncthreads();
    #pragma unroll
    for (int off = 1; off < 1024; off <<= 1) {
        int t = (tid >= off) ? tmp[tid - off] : 0;
        __syncthreads();
        tmp[tid] += t;
        __syncthreads();
    }
    int excl = partial[blockIdx.x] + tmp[tid] - v;
    if (idx < NN) { row_ptr[idx] = excl; cursor[idx] = excl; }
}

// ---------------- CSR fill with precomputed symmetric weights ----------------
__global__ void fill_csr(const int* __restrict__ src, const int* __restrict__ dst,
                         const float* __restrict__ dinv,
                         int* __restrict__ cursor, int2* __restrict__ cw) {
    int e = blockIdx.x * 256 + threadIdx.x;
    if (e < EE) {
        int u = src[e], v = dst[e];
        int pos = atomicAdd(&cursor[v], 1);
        float w = dinv[u] * dinv[v];
        cw[pos] = make_int2(u, __float_as_int(w));
    }
}

// ---------------- dense transform: T = X @ W, output bf16 (16 rows / block) ----------------
template <int K>
__global__ __launch_bounds__(256) void gemm_k(const float* __restrict__ X,
                                              const float* __restrict__ W,
                                              unsigned short* __restrict__ T2) {
    __shared__ float sW[K * 64];
    __shared__ float sX[16 * K];
    int tid = threadIdx.x;
    size_t row0 = (size_t)blockIdx.x * 16;
    for (int i = tid; i < K * 64; i += 256) sW[i] = W[i];
    for (int i = tid; i < 16 * K; i += 256) sX[i] = X[row0 * K + i];
    __syncthreads();
    int rg = tid >> 6, c = tid & 63;
    #pragma unroll
    for (int r = rg; r < 16; r += 4) {
        const float* xr = &sX[r * K];
        float acc = 0.f;
        #pragma unroll
        for (int k = 0; k < K; ++k) acc = fmaf(xr[k], sW[k * 64 + c], acc);
        T2[(row0 + r) * 64 + c] = f2bf(acc);
    }
}

// ---------------- aggregation (bf16 gather) ----------------
// One wave per node. 8 groups of 8 lanes; group g handles edge j=beg+i*8+g;
// lane fl loads uint4 (16 B = 8 bf16 feats) of the 128 B source row.
__global__ __launch_bounds__(256) void agg_k(const uint4* __restrict__ T4,   // [N*8] uint4
                                             const float* __restrict__ dinv,
                                             const int* __restrict__ row_ptr,
                                             const int2* __restrict__ cw,
                                             const float* __restrict__ bias,
                                             float4* __restrict__ A4) {
    int node = blockIdx.x * 4 + (threadIdx.x >> 6);
    int lane = threadIdx.x & 63;
    int grp  = lane >> 3;      // 0..7 : edge slot
    int fl   = lane & 7;       // which 8-feature chunk
    int beg = row_ptr[node], end = row_ptr[node + 1];
    float a0=0,a1=0,a2=0,a3=0,a4=0,a5=0,a6=0,a7=0;
    for (int j = beg + grp; j < end; j += 8) {
        int2 c = cw[j];
        float w = __int_as_float(c.y);
        uint4 t = T4[(size_t)c.x * 8 + fl];
        a0 = fmaf(bflo(t.x), w, a0); a1 = fmaf(bfhi(t.x), w, a1);
        a2 = fmaf(bflo(t.y), w, a2); a3 = fmaf(bfhi(t.y), w, a3);
        a4 = fmaf(bflo(t.z), w, a4); a5 = fmaf(bfhi(t.z), w, a5);
        a6 = fmaf(bflo(t.w), w, a6); a7 = fmaf(bfhi(t.w), w, a7);
    }
    // butterfly-sum the 8 groups (lanes xor 8, 16, 32)
    #pragma unroll
    for (int m = 8; m <= 32; m <<= 1) {
        a0 += __shfl_xor(a0, m); a1 += __shfl_xor(a1, m);
        a2 += __shfl_xor(a2, m); a3 += __shfl_xor(a3, m);
        a4 += __shfl_xor(a4, m); a5 += __shfl_xor(a5, m);
        a6 += __shfl_xor(a6, m); a7 += __shfl_xor(a7, m);
    }
    if (grp == 0) {   // lanes 0..7 write the 64-float row (32 B each)
        float dv = dinv[node];
        float s = dv * dv;
        uint4 t = T4[(size_t)node * 8 + fl];
        const float* b = &bias[fl * 8];
        float4 o0, o1;
        o0.x = tanhf(fmaf(bflo(t.x), s, a0) + b[0]);
        o0.y = tanhf(fmaf(bfhi(t.x), s, a1) + b[1]);
        o0.z = tanhf(fmaf(bflo(t.y), s, a2) + b[2]);
        o0.w = tanhf(fmaf(bfhi(t.y), s, a3) + b[3]);
        o1.x = tanhf(fmaf(bflo(t.z), s, a4) + b[4]);
        o1.y = tanhf(fmaf(bfhi(t.z), s, a5) + b[5]);
        o1.z = tanhf(fmaf(bflo(t.w), s, a6) + b[6]);
        o1.w = tanhf(fmaf(bfhi(t.w), s, a7) + b[7]);
        A4[(size_t)node * 16 + fl * 2]     = o0;
        A4[(size_t)node * 16 + fl * 2 + 1] = o1;
    }
}

// ---------------- pooling ----------------
__global__ void hist_batch(const int* __restrict__ batch, int* counts) {
    int i = blockIdx.x * 256 + threadIdx.x;
    if (i < NN) atomicAdd(&counts[batch[i]], 1);
}

__global__ void scan_counts(const int* __restrict__ counts, int* __restrict__ gstart) {
    __shared__ int tmp[GG];
    int tid = threadIdx.x;
    int v = counts[tid];
    tmp[tid] = v;
    __syncthreads();
    #pragma unroll
    for (int off = 1; off < GG; off <<= 1) {
        int t = (tid >= off) ? tmp[tid - off] : 0;
        __syncthreads();
        tmp[tid] += t;
        __syncthreads();
    }
    gstart[tid] = tmp[tid] - v;                    // exclusive
    if (tid == GG - 1) gstart[GG] = tmp[GG - 1];   // == NN
}

__global__ __launch_bounds__(256) void pool_k(const float* __restrict__ H,
                                              const int* __restrict__ gstart,
                                              float* __restrict__ hidden) {
    __shared__ float smax[4][64], ssum[4][64];
    int g = blockIdx.x;
    int wave = threadIdx.x >> 6, lane = threadIdx.x & 63;
    int beg = gstart[g], end = gstart[g + 1];
    float mx = -FLT_MAX, sm = 0.f;
    for (int i = beg + wave; i < end; i += 4) {
        float v = H[(size_t)i * 64 + lane];
        mx = fmaxf(mx, v);
        sm += v;
    }
    smax[wave][lane] = mx; ssum[wave][lane] = sm;
    __syncthreads();
    if (wave == 0) {
        mx = fmaxf(fmaxf(smax[0][lane], smax[1][lane]), fmaxf(smax[2][lane], smax[3][lane]));
        sm = ssum[0][lane] + ssum[1][lane] + ssum[2][lane] + ssum[3][lane];
        int cnt = end - beg;
        hidden[g * 128 + lane]      = (cnt > 0) ? mx : 0.f;
        hidden[g * 128 + 64 + lane] = sm / fmaxf((float)cnt, 1.f);
    }
}

__global__ void head_k(const float* __restrict__ hidden, const float* __restrict__ Wout,
                       const float* __restrict__ bout, float* __restrict__ out) {
    int g = blockIdx.x, lane = threadIdx.x;   // 64 threads
    float v = hidden[g * 128 + lane] * Wout[lane]
            + hidden[g * 128 + 64 + lane] * Wout[64 + lane];
    #pragma unroll
    for (int off = 32; off; off >>= 1) v += __shfl_down(v, off);
    if (lane == 0) out[g] = 1.f / (1.f + expf(-(v + bout[0])));
}

// ---------------- launch ----------------
extern "C" void kernel_launch(void* const* d_in, const int* in_sizes, int n_in,
                              void* d_out, int out_size, void* d_ws, size_t ws_size,
                              hipStream_t stream) {
    const float* x     = (const float*)d_in[0];
    const int*   ei    = (const int*)d_in[1];
    const int*   src   = ei;
    const int*   dst   = ei + EE;
    const int*   batch = (const int*)d_in[2];
    const float* W0 = (const float*)d_in[4];  const float* b0 = (const float*)d_in[5];
    const float* W1 = (const float*)d_in[6];  const float* b1 = (const float*)d_in[7];
    const float* W2 = (const float*)d_in[8];  const float* b2 = (const float*)d_in[9];
    const float* W3 = (const float*)d_in[10]; const float* b3 = (const float*)d_in[11];
    const float* Wout = (const float*)d_in[12]; const float* bout = (const float*)d_in[13];

    float* out    = (float*)d_out;
    float* hidden = out + GG;     // [G,128] portion of d_out

    char*  w = (char*)d_ws;
    size_t off = 0;
    auto alloc = [&](size_t bytes) -> char* {
        char* p = w + off;
        off = (off + bytes + 255) & ~(size_t)255;
        return p;
    };
    int*   degi    = (int*)  alloc(NN * 4);
    float* dinv    = (float*)alloc(NN * 4);
    int*   row_ptr = (int*)  alloc((NN + 1) * 4);
    int*   cursor  = (int*)  alloc(NN * 4);
    int*   partial = (int*)  alloc(NBLK * 4);
    int2*  cw      = (int2*) alloc((size_t)EE * 8);
    unsigned short* T2 = (unsigned short*)alloc((size_t)NN * 64 * 2);   // bf16
    float* A       = (float*)alloc((size_t)NN * 64 * 4);
    int*   counts  = (int*)  alloc(GG * 4);
    int*   gstart  = (int*)  alloc((GG + 1) * 4);
    (void)ws_size; (void)in_sizes; (void)n_in; (void)out_size;

    // degree + CSR offsets (hierarchical scan)
    init_deg<<<(NN + 255) / 256, 256, 0, stream>>>(degi);
    edge_deg<<<(EE + 255) / 256, 256, 0, stream>>>(dst, degi);
    scan_partial<<<NBLK, 1024, 0, stream>>>(degi, partial);
    scan_offsets<<<1, 128, 0, stream>>>(partial, row_ptr);
    scan_final<<<NBLK, 1024, 0, stream>>>(degi, partial, row_ptr, cursor);
    make_dinv<<<(NN + 255) / 256, 256, 0, stream>>>(degi, dinv);
    fill_csr<<<(EE + 255) / 256, 256, 0, stream>>>(src, dst, dinv, cursor, cw);

    // pooling prep
    hipMemsetAsync(counts, 0, GG * sizeof(int), stream);
    hist_batch<<<(NN + 255) / 256, 256, 0, stream>>>(batch, counts);
    scan_counts<<<1, GG, 0, stream>>>(counts, gstart);

    // 4 GCN layers (transform(bf16) -> aggregate+bias+tanh)
    gemm_k<FF><<<NN / 16, 256, 0, stream>>>(x, W0, T2);
    agg_k<<<NN / 4, 256, 0, stream>>>((const uint4*)T2, dinv, row_ptr, cw, b0, (float4*)A);
    gemm_k<DD><<<NN / 16, 256, 0, stream>>>(A, W1, T2);
    agg_k<<<NN / 4, 256, 0, stream>>>((const uint4*)T2, dinv, row_ptr, cw, b1, (float4*)A);
    gemm_k<DD><<<NN / 16, 256, 0, stream>>>(A, W2, T2);
    agg_k<<<NN / 4, 256, 0, stream>>>((const uint4*)T2, dinv, row_ptr, cw, b2, (float4*)A);
    gemm_k<DD><<<NN / 16, 256, 0, stream>>>(A, W3, T2);
    agg_k<<<NN / 4, 256, 0, stream>>>((const uint4*)T2, dinv, row_ptr, cw, b3, (float4*)A);

    // pooling + head
    pool_k<<<GG, 256, 0, stream>>>(A, gstart, hidden);
    head_k<<<GG, 64, 0, stream>>>(hidden, Wout, bout, out);
}

// Round 8
// 748.668 us; speedup vs baseline: 2.0000x; 1.1371x over previous
//
#include <hip/hip_runtime.h>
#include <math.h>
#include <float.h>

// Problem constants (fixed by setup_inputs)
#define NN 100000
#define EE 1600000
#define FF 128
#define DD 64
#define GG 512
#define NBLK 98   // ceil(NN/1024)

__device__ __forceinline__ unsigned short f2bf(float f) {
    unsigned u = __float_as_uint(f);
    u = (u + 0x7fff + ((u >> 16) & 1)) >> 16;   // round-to-nearest-even
    return (unsigned short)u;
}
__device__ __forceinline__ float bflo(unsigned u) { return __uint_as_float(u << 16); }
__device__ __forceinline__ float bfhi(unsigned u) { return __uint_as_float(u & 0xffff0000u); }

// ---------------- degree ----------------
__global__ void init_deg(int* degi) {
    int i = blockIdx.x * 256 + threadIdx.x;
    if (i < NN) degi[i] = 1;   // self loop
}

__global__ void edge_deg(const int* __restrict__ dst, int* degi) {
    int e = blockIdx.x * 256 + threadIdx.x;
    if (e < EE) atomicAdd(&degi[dst[e]], 1);
}

__global__ void make_dinv(const int* __restrict__ degi, float* __restrict__ dinv) {
    int i = blockIdx.x * 256 + threadIdx.x;
    if (i < NN) dinv[i] = rsqrtf((float)degi[i]);   // deg >= 1 always
}

// ---------------- hierarchical exclusive scan of indeg = degi-1 ----------------
__global__ void scan_partial(const int* __restrict__ degi, int* __restrict__ partial) {
    __shared__ int red[1024];
    int tid = threadIdx.x;
    int idx = blockIdx.x * 1024 + tid;
    red[tid] = (idx < NN) ? degi[idx] - 1 : 0;
    __syncthreads();
    #pragma unroll
    for (int off = 512; off; off >>= 1) {
        if (tid < off) red[tid] += red[tid + off];
        __syncthreads();
    }
    if (tid == 0) partial[blockIdx.x] = red[0];
}

__global__ void scan_offsets(int* __restrict__ partial, int* __restrict__ row_ptr) {
    __shared__ int tmp[128];
    int tid = threadIdx.x;   // 128 threads
    int v = (tid < NBLK) ? partial[tid] : 0;
    tmp[tid] = v;
    __syncthreads();
    #pragma unroll
    for (int off = 1; off < 128; off <<= 1) {
        int t = (tid >= off) ? tmp[tid - off] : 0;
        __syncthreads();
        tmp[tid] += t;
        __syncthreads();
    }
    if (tid < NBLK) partial[tid] = tmp[tid] - v;     // exclusive block offsets
    if (tid == NBLK - 1) row_ptr[NN] = tmp[tid];     // total == EE
}

__global__ void scan_final(const int* __restrict__ degi, const int* __restrict__ partial,
                           int* __restrict__ row_ptr, int* __restrict__ cursor) {
    __shared__ int tmp[1024];
    int tid = threadIdx.x;
    int idx = blockIdx.x * 1024 + tid;
    int v = (idx < NN) ? degi[idx] - 1 : 0;
    tmp[tid] = v;
    __syncthreads();
    #pragma unroll
    for (int off = 1; off < 1024; off <<= 1) {
        int t = (tid >= off) ? tmp[tid - off] : 0;
        __syncthreads();
        tmp[tid] += t;
        __syncthreads();
    }
    int excl = partial[blockIdx.x] + tmp[tid] - v;
    if (idx < NN) { row_ptr[idx] = excl; cursor[idx] = excl; }
}

// ---------------- CSR fill with precomputed symmetric weights ----------------
__global__ void fill_csr(const int* __restrict__ src, const int* __restrict__ dst,
                         const float* __restrict__ dinv,
                         int* __restrict__ cursor, int2* __restrict__ cw) {
    int e = blockIdx.x * 256 + threadIdx.x;
    if (e < EE) {
        int u = src[e], v = dst[e];
        int pos = atomicAdd(&cursor[v], 1);
        float w = dinv[u] * dinv[v];
        cw[pos] = make_int2(u, __float_as_int(w));
    }
}

// ---------------- dense transform: T = X @ W, bf16 out ----------------
// 64x64 output tile / block, 256 threads, 4x4 register tile per thread.
// K staged in 64-wide slabs (33 KB LDS -> 4 blocks/CU).
template <int K>
__global__ __launch_bounds__(256) void gemm_k(const float* __restrict__ X,
                                              const float* __restrict__ W,
                                              unsigned short* __restrict__ T2) {
    __shared__ float sX[64 * 65];   // [r][k], stride 65 (bank spread + b32 reads)
    __shared__ float sW[64 * 64];   // [k][c], contiguous (b128 reads)
    int tid = threadIdx.x;
    int row0 = blockIdx.x * 64;
    int rows = NN - row0; if (rows > 64) rows = 64;
    int r0 = (tid >> 4) << 2;       // 0,4,..,60
    int c0 = (tid & 15) << 2;       // 0,4,..,60
    float acc[4][4] = {};
    for (int k0 = 0; k0 < K; k0 += 64) {
        // stage W slab (linear, coalesced float4)
        {
            const float4* Wg = (const float4*)(W + (size_t)k0 * 64);
            float4* sW4 = (float4*)sW;
            #pragma unroll
            for (int j = 0; j < 4; ++j) sW4[tid + j * 256] = Wg[tid + j * 256];
        }
        // stage X slab: 64 rows x 64 k (float4 global reads, b32 LDS writes)
        #pragma unroll
        for (int j = 0; j < 4; ++j) {
            int flat = tid + j * 256;          // 0..1023
            int r = flat >> 4, kc = (flat & 15) << 2;
            float4 v = make_float4(0.f, 0.f, 0.f, 0.f);
            if (r < rows) v = *(const float4*)(X + (size_t)(row0 + r) * K + k0 + kc);
            sX[r * 65 + kc]     = v.x;
            sX[r * 65 + kc + 1] = v.y;
            sX[r * 65 + kc + 2] = v.z;
            sX[r * 65 + kc + 3] = v.w;
        }
        __syncthreads();
        #pragma unroll 8
        for (int k = 0; k < 64; ++k) {
            float4 b = *(const float4*)(sW + k * 64 + c0);
            float a0 = sX[r0 * 65 + k];
            float a1 = sX[(r0 + 1) * 65 + k];
            float a2 = sX[(r0 + 2) * 65 + k];
            float a3 = sX[(r0 + 3) * 65 + k];
            acc[0][0] = fmaf(a0, b.x, acc[0][0]); acc[0][1] = fmaf(a0, b.y, acc[0][1]);
            acc[0][2] = fmaf(a0, b.z, acc[0][2]); acc[0][3] = fmaf(a0, b.w, acc[0][3]);
            acc[1][0] = fmaf(a1, b.x, acc[1][0]); acc[1][1] = fmaf(a1, b.y, acc[1][1]);
            acc[1][2] = fmaf(a1, b.z, acc[1][2]); acc[1][3] = fmaf(a1, b.w, acc[1][3]);
            acc[2][0] = fmaf(a2, b.x, acc[2][0]); acc[2][1] = fmaf(a2, b.y, acc[2][1]);
            acc[2][2] = fmaf(a2, b.z, acc[2][2]); acc[2][3] = fmaf(a2, b.w, acc[2][3]);
            acc[3][0] = fmaf(a3, b.x, acc[3][0]); acc[3][1] = fmaf(a3, b.y, acc[3][1]);
            acc[3][2] = fmaf(a3, b.z, acc[3][2]); acc[3][3] = fmaf(a3, b.w, acc[3][3]);
        }
        __syncthreads();
    }
    #pragma unroll
    for (int i = 0; i < 4; ++i) {
        int r = row0 + r0 + i;
        if (r < NN) {
            ushort4 o;
            o.x = f2bf(acc[i][0]); o.y = f2bf(acc[i][1]);
            o.z = f2bf(acc[i][2]); o.w = f2bf(acc[i][3]);
            *(ushort4*)(T2 + (size_t)r * 64 + c0) = o;
        }
    }
}

// ---------------- aggregation (bf16 gather) ----------------
// One wave per node. 8 groups of 8 lanes; group g handles edge j=beg+i*8+g;
// lane fl loads uint4 (16 B = 8 bf16 feats) of the 128 B source row.
__global__ __launch_bounds__(256) void agg_k(const uint4* __restrict__ T4,   // [N*8] uint4
                                             const float* __restrict__ dinv,
                                             const int* __restrict__ row_ptr,
                                             const int2* __restrict__ cw,
                                             const float* __restrict__ bias,
                                             float4* __restrict__ A4) {
    int node = blockIdx.x * 4 + (threadIdx.x >> 6);
    int lane = threadIdx.x & 63;
    int grp  = lane >> 3;      // 0..7 : edge slot
    int fl   = lane & 7;       // which 8-feature chunk
    int beg = row_ptr[node], end = row_ptr[node + 1];
    float a0=0,a1=0,a2=0,a3=0,a4=0,a5=0,a6=0,a7=0;
    for (int j = beg + grp; j < end; j += 8) {
        int2 c = cw[j];
        float w = __int_as_float(c.y);
        uint4 t = T4[(size_t)c.x * 8 + fl];
        a0 = fmaf(bflo(t.x), w, a0); a1 = fmaf(bfhi(t.x), w, a1);
        a2 = fmaf(bflo(t.y), w, a2); a3 = fmaf(bfhi(t.y), w, a3);
        a4 = fmaf(bflo(t.z), w, a4); a5 = fmaf(bfhi(t.z), w, a5);
        a6 = fmaf(bflo(t.w), w, a6); a7 = fmaf(bfhi(t.w), w, a7);
    }
    // butterfly-sum the 8 groups (lanes xor 8, 16, 32)
    #pragma unroll
    for (int m = 8; m <= 32; m <<= 1) {
        a0 += __shfl_xor(a0, m); a1 += __shfl_xor(a1, m);
        a2 += __shfl_xor(a2, m); a3 += __shfl_xor(a3, m);
        a4 += __shfl_xor(a4, m); a5 += __shfl_xor(a5, m);
        a6 += __shfl_xor(a6, m); a7 += __shfl_xor(a7, m);
    }
    if (grp == 0) {   // lanes 0..7 write the 64-float row (32 B each)
        float dv = dinv[node];
        float s = dv * dv;
        uint4 t = T4[(size_t)node * 8 + fl];
        const float* b = &bias[fl * 8];
        float4 o0, o1;
        o0.x = tanhf(fmaf(bflo(t.x), s, a0) + b[0]);
        o0.y = tanhf(fmaf(bfhi(t.x), s, a1) + b[1]);
        o0.z = tanhf(fmaf(bflo(t.y), s, a2) + b[2]);
        o0.w = tanhf(fmaf(bfhi(t.y), s, a3) + b[3]);
        o1.x = tanhf(fmaf(bflo(t.z), s, a4) + b[4]);
        o1.y = tanhf(fmaf(bfhi(t.z), s, a5) + b[5]);
        o1.z = tanhf(fmaf(bflo(t.w), s, a6) + b[6]);
        o1.w = tanhf(fmaf(bfhi(t.w), s, a7) + b[7]);
        A4[(size_t)node * 16 + fl * 2]     = o0;
        A4[(size_t)node * 16 + fl * 2 + 1] = o1;
    }
}

// ---------------- pooling ----------------
__global__ void hist_batch(const int* __restrict__ batch, int* counts) {
    int i = blockIdx.x * 256 + threadIdx.x;
    if (i < NN) atomicAdd(&counts[batch[i]], 1);
}

__global__ void scan_counts(const int* __restrict__ counts, int* __restrict__ gstart) {
    __shared__ int tmp[GG];
    int tid = threadIdx.x;
    int v = counts[tid];
    tmp[tid] = v;
    __syncthreads();
    #pragma unroll
    for (int off = 1; off < GG; off <<= 1) {
        int t = (tid >= off) ? tmp[tid - off] : 0;
        __syncthreads();
        tmp[tid] += t;
        __syncthreads();
    }
    gstart[tid] = tmp[tid] - v;                    // exclusive
    if (tid == GG - 1) gstart[GG] = tmp[GG - 1];   // == NN
}

__global__ __launch_bounds__(256) void pool_k(const float* __restrict__ H,
                                              const int* __restrict__ gstart,
                                              float* __restrict__ hidden) {
    __shared__ float smax[4][64], ssum[4][64];
    int g = blockIdx.x;
    int wave = threadIdx.x >> 6, lane = threadIdx.x & 63;
    int beg = gstart[g], end = gstart[g + 1];
    float mx = -FLT_MAX, sm = 0.f;
    for (int i = beg + wave; i < end; i += 4) {
        float v = H[(size_t)i * 64 + lane];
        mx = fmaxf(mx, v);
        sm += v;
    }
    smax[wave][lane] = mx; ssum[wave][lane] = sm;
    __syncthreads();
    if (wave == 0) {
        mx = fmaxf(fmaxf(smax[0][lane], smax[1][lane]), fmaxf(smax[2][lane], smax[3][lane]));
        sm = ssum[0][lane] + ssum[1][lane] + ssum[2][lane] + ssum[3][lane];
        int cnt = end - beg;
        hidden[g * 128 + lane]      = (cnt > 0) ? mx : 0.f;
        hidden[g * 128 + 64 + lane] = sm / fmaxf((float)cnt, 1.f);
    }
}

__global__ void head_k(const float* __restrict__ hidden, const float* __restrict__ Wout,
                       const float* __restrict__ bout, float* __restrict__ out) {
    int g = blockIdx.x, lane = threadIdx.x;   // 64 threads
    float v = hidden[g * 128 + lane] * Wout[lane]
            + hidden[g * 128 + 64 + lane] * Wout[64 + lane];
    #pragma unroll
    for (int off = 32; off; off >>= 1) v += __shfl_down(v, off);
    if (lane == 0) out[g] = 1.f / (1.f + expf(-(v + bout[0])));
}

// ---------------- launch ----------------
extern "C" void kernel_launch(void* const* d_in, const int* in_sizes, int n_in,
                              void* d_out, int out_size, void* d_ws, size_t ws_size,
                              hipStream_t stream) {
    const float* x     = (const float*)d_in[0];
    const int*   ei    = (const int*)d_in[1];
    const int*   src   = ei;
    const int*   dst   = ei + EE;
    const int*   batch = (const int*)d_in[2];
    const float* W0 = (const float*)d_in[4];  const float* b0 = (const float*)d_in[5];
    const float* W1 = (const float*)d_in[6];  const float* b1 = (const float*)d_in[7];
    const float* W2 = (const float*)d_in[8];  const float* b2 = (const float*)d_in[9];
    const float* W3 = (const float*)d_in[10]; const float* b3 = (const float*)d_in[11];
    const float* Wout = (const float*)d_in[12]; const float* bout = (const float*)d_in[13];

    float* out    = (float*)d_out;
    float* hidden = out + GG;     // [G,128] portion of d_out

    char*  w = (char*)d_ws;
    size_t off = 0;
    auto alloc = [&](size_t bytes) -> char* {
        char* p = w + off;
        off = (off + bytes + 255) & ~(size_t)255;
        return p;
    };
    int*   degi    = (int*)  alloc(NN * 4);
    float* dinv    = (float*)alloc(NN * 4);
    int*   row_ptr = (int*)  alloc((NN + 1) * 4);
    int*   cursor  = (int*)  alloc(NN * 4);
    int*   partial = (int*)  alloc(NBLK * 4);
    int2*  cw      = (int2*) alloc((size_t)EE * 8);
    unsigned short* T2 = (unsigned short*)alloc((size_t)NN * 64 * 2);   // bf16
    float* A       = (float*)alloc((size_t)NN * 64 * 4);
    int*   counts  = (int*)  alloc(GG * 4);
    int*   gstart  = (int*)  alloc((GG + 1) * 4);
    (void)ws_size; (void)in_sizes; (void)n_in; (void)out_size;

    // degree + CSR offsets (hierarchical scan)
    init_deg<<<(NN + 255) / 256, 256, 0, stream>>>(degi);
    edge_deg<<<(EE + 255) / 256, 256, 0, stream>>>(dst, degi);
    scan_partial<<<NBLK, 1024, 0, stream>>>(degi, partial);
    scan_offsets<<<1, 128, 0, stream>>>(partial, row_ptr);
    scan_final<<<NBLK, 1024, 0, stream>>>(degi, partial, row_ptr, cursor);
    make_dinv<<<(NN + 255) / 256, 256, 0, stream>>>(degi, dinv);
    fill_csr<<<(EE + 255) / 256, 256, 0, stream>>>(src, dst, dinv, cursor, cw);

    // pooling prep
    hipMemsetAsync(counts, 0, GG * sizeof(int), stream);
    hist_batch<<<(NN + 255) / 256, 256, 0, stream>>>(batch, counts);
    scan_counts<<<1, GG, 0, stream>>>(counts, gstart);

    // 4 GCN layers (transform(bf16) -> aggregate+bias+tanh)
    const int GB = (NN + 63) / 64;
    gemm_k<FF><<<GB, 256, 0, stream>>>(x, W0, T2);
    agg_k<<<NN / 4, 256, 0, stream>>>((const uint4*)T2, dinv, row_ptr, cw, b0, (float4*)A);
    gemm_k<DD><<<GB, 256, 0, stream>>>(A, W1, T2);
    agg_k<<<NN / 4, 256, 0, stream>>>((const uint4*)T2, dinv, row_ptr, cw, b1, (float4*)A);
    gemm_k<DD><<<GB, 256, 0, stream>>>(A, W2, T2);
    agg_k<<<NN / 4, 256, 0, stream>>>((const uint4*)T2, dinv, row_ptr, cw, b2, (float4*)A);
    gemm_k<DD><<<GB, 256, 0, stream>>>(A, W3, T2);
    agg_k<<<NN / 4, 256, 0, stream>>>((const uint4*)T2, dinv, row_ptr, cw, b3, (float4*)A);

    // pooling + head
    pool_k<<<GG, 256, 0, stream>>>(A, gstart, hidden);
    head_k<<<GG, 64, 0, stream>>>(hidden, Wout, bout, out);
}

// Round 10
// 655.767 us; speedup vs baseline: 2.2833x; 1.1417x over previous
//
#include <hip/hip_runtime.h>
#include <math.h>
#include <float.h>

// Problem constants (fixed by setup_inputs)
#define NN 100000
#define EE 1600000
#define FF 128
#define DD 64
#define GG 512
#define NBLK 98   // ceil(NN/1024)

__device__ __forceinline__ unsigned short f2bf(float f) {
    unsigned u = __float_as_uint(f);
    u = (u + 0x7fff + ((u >> 16) & 1)) >> 16;   // round-to-nearest-even
    return (unsigned short)u;
}
__device__ __forceinline__ float bflo(unsigned u) { return __uint_as_float(u << 16); }
__device__ __forceinline__ float bfhi(unsigned u) { return __uint_as_float(u & 0xffff0000u); }

// ---------------- degree ----------------
__global__ void init_deg(int* degi) {
    int i = blockIdx.x * 256 + threadIdx.x;
    if (i < NN) degi[i] = 1;   // self loop
}

__global__ void edge_deg(const int* __restrict__ dst, int* degi) {
    int e = blockIdx.x * 256 + threadIdx.x;
    if (e < EE) atomicAdd(&degi[dst[e]], 1);
}

__global__ void make_dinv(const int* __restrict__ degi, float* __restrict__ dinv) {
    int i = blockIdx.x * 256 + threadIdx.x;
    if (i < NN) dinv[i] = rsqrtf((float)degi[i]);   // deg >= 1 always
}

// ---------------- hierarchical exclusive scan of indeg = degi-1 ----------------
__global__ void scan_partial(const int* __restrict__ degi, int* __restrict__ partial) {
    __shared__ int red[1024];
    int tid = threadIdx.x;
    int idx = blockIdx.x * 1024 + tid;
    red[tid] = (idx < NN) ? degi[idx] - 1 : 0;
    __syncthreads();
    #pragma unroll
    for (int off = 512; off; off >>= 1) {
        if (tid < off) red[tid] += red[tid + off];
        __syncthreads();
    }
    if (tid == 0) partial[blockIdx.x] = red[0];
}

__global__ void scan_offsets(int* __restrict__ partial, int* __restrict__ row_ptr) {
    __shared__ int tmp[128];
    int tid = threadIdx.x;   // 128 threads
    int v = (tid < NBLK) ? partial[tid] : 0;
    tmp[tid] = v;
    __syncthreads();
    #pragma unroll
    for (int off = 1; off < 128; off <<= 1) {
        int t = (tid >= off) ? tmp[tid - off] : 0;
        __syncthreads();
        tmp[tid] += t;
        __syncthreads();
    }
    if (tid < NBLK) partial[tid] = tmp[tid] - v;     // exclusive block offsets
    if (tid == NBLK - 1) row_ptr[NN] = tmp[tid];     // total == EE
}

__global__ void scan_final(const int* __restrict__ degi, const int* __restrict__ partial,
                           int* __restrict__ row_ptr, int* __restrict__ cursor) {
    __shared__ int tmp[1024];
    int tid = threadIdx.x;
    int idx = blockIdx.x * 1024 + tid;
    int v = (idx < NN) ? degi[idx] - 1 : 0;
    tmp[tid] = v;
    __syncthreads();
    #pragma unroll
    for (int off = 1; off < 1024; off <<= 1) {
        int t = (tid >= off) ? tmp[tid - off] : 0;
        __syncthreads();
        tmp[tid] += t;
        __syncthreads();
    }
    int excl = partial[blockIdx.x] + tmp[tid] - v;
    if (idx < NN) { row_ptr[idx] = excl; cursor[idx] = excl; }
}

// ---------------- CSR fill with precomputed symmetric weights ----------------
__global__ void fill_csr(const int* __restrict__ src, const int* __restrict__ dst,
                         const float* __restrict__ dinv,
                         int* __restrict__ cursor, int2* __restrict__ cw) {
    int e = blockIdx.x * 256 + threadIdx.x;
    if (e < EE) {
        int u = src[e], v = dst[e];
        int pos = atomicAdd(&cursor[v], 1);
        float w = dinv[u] * dinv[v];
        cw[pos] = make_int2(u, __float_as_int(w));
    }
}

// ---------------- dense transform: T = X @ W, bf16 out ----------------
// 64x64 output tile / block, 256 threads, 4x4 register tile per thread.
// K staged in 64-wide slabs (33 KB LDS -> 4 blocks/CU).
template <int K>
__global__ __launch_bounds__(256) void gemm_k(const float* __restrict__ X,
                                              const float* __restrict__ W,
                                              unsigned short* __restrict__ T2) {
    __shared__ float sX[64 * 65];   // [r][k], stride 65 (bank spread + b32 reads)
    __shared__ float sW[64 * 64];   // [k][c], contiguous (b128 reads)
    int tid = threadIdx.x;
    int row0 = blockIdx.x * 64;
    int rows = NN - row0; if (rows > 64) rows = 64;
    int r0 = (tid >> 4) << 2;       // 0,4,..,60
    int c0 = (tid & 15) << 2;       // 0,4,..,60
    float acc[4][4] = {};
    for (int k0 = 0; k0 < K; k0 += 64) {
        // stage W slab (linear, coalesced float4)
        {
            const float4* Wg = (const float4*)(W + (size_t)k0 * 64);
            float4* sW4 = (float4*)sW;
            #pragma unroll
            for (int j = 0; j < 4; ++j) sW4[tid + j * 256] = Wg[tid + j * 256];
        }
        // stage X slab: 64 rows x 64 k (float4 global reads, b32 LDS writes)
        #pragma unroll
        for (int j = 0; j < 4; ++j) {
            int flat = tid + j * 256;          // 0..1023
            int r = flat >> 4, kc = (flat & 15) << 2;
            float4 v = make_float4(0.f, 0.f, 0.f, 0.f);
            if (r < rows) v = *(const float4*)(X + (size_t)(row0 + r) * K + k0 + kc);
            sX[r * 65 + kc]     = v.x;
            sX[r * 65 + kc + 1] = v.y;
            sX[r * 65 + kc + 2] = v.z;
            sX[r * 65 + kc + 3] = v.w;
        }
        __syncthreads();
        #pragma unroll 8
        for (int k = 0; k < 64; ++k) {
            float4 b = *(const float4*)(sW + k * 64 + c0);
            float a0 = sX[r0 * 65 + k];
            float a1 = sX[(r0 + 1) * 65 + k];
            float a2 = sX[(r0 + 2) * 65 + k];
            float a3 = sX[(r0 + 3) * 65 + k];
            acc[0][0] = fmaf(a0, b.x, acc[0][0]); acc[0][1] = fmaf(a0, b.y, acc[0][1]);
            acc[0][2] = fmaf(a0, b.z, acc[0][2]); acc[0][3] = fmaf(a0, b.w, acc[0][3]);
            acc[1][0] = fmaf(a1, b.x, acc[1][0]); acc[1][1] = fmaf(a1, b.y, acc[1][1]);
            acc[1][2] = fmaf(a1, b.z, acc[1][2]); acc[1][3] = fmaf(a1, b.w, acc[1][3]);
            acc[2][0] = fmaf(a2, b.x, acc[2][0]); acc[2][1] = fmaf(a2, b.y, acc[2][1]);
            acc[2][2] = fmaf(a2, b.z, acc[2][2]); acc[2][3] = fmaf(a2, b.w, acc[2][3]);
            acc[3][0] = fmaf(a3, b.x, acc[3][0]); acc[3][1] = fmaf(a3, b.y, acc[3][1]);
            acc[3][2] = fmaf(a3, b.z, acc[3][2]); acc[3][3] = fmaf(a3, b.w, acc[3][3]);
        }
        __syncthreads();
    }
    #pragma unroll
    for (int i = 0; i < 4; ++i) {
        int r = row0 + r0 + i;
        if (r < NN) {
            ushort4 o;
            o.x = f2bf(acc[i][0]); o.y = f2bf(acc[i][1]);
            o.z = f2bf(acc[i][2]); o.w = f2bf(acc[i][3]);
            *(ushort4*)(T2 + (size_t)r * 64 + c0) = o;
        }
    }
}

// ---------------- aggregation (bf16 gather) ----------------
// One wave per node. 8 groups of 8 lanes; group g handles edge j=beg+i*8+g;
// lane fl loads uint4 (16 B = 8 bf16 feats) of the 128 B source row.
__global__ __launch_bounds__(256) void agg_k(const uint4* __restrict__ T4,   // [N*8] uint4
                                             const float* __restrict__ dinv,
                                             const int* __restrict__ row_ptr,
                                             const int2* __restrict__ cw,
                                             const float* __restrict__ bias,
                                             float4* __restrict__ A4) {
    int node = blockIdx.x * 4 + (threadIdx.x >> 6);
    int lane = threadIdx.x & 63;
    int grp  = lane >> 3;      // 0..7 : edge slot
    int fl   = lane & 7;       // which 8-feature chunk
    int beg = row_ptr[node], end = row_ptr[node + 1];
    float a0=0,a1=0,a2=0,a3=0,a4=0,a5=0,a6=0,a7=0;
    for (int j = beg + grp; j < end; j += 8) {
        int2 c = cw[j];
        float w = __int_as_float(c.y);
        uint4 t = T4[(size_t)c.x * 8 + fl];
        a0 = fmaf(bflo(t.x), w, a0); a1 = fmaf(bfhi(t.x), w, a1);
        a2 = fmaf(bflo(t.y), w, a2); a3 = fmaf(bfhi(t.y), w, a3);
        a4 = fmaf(bflo(t.z), w, a4); a5 = fmaf(bfhi(t.z), w, a5);
        a6 = fmaf(bflo(t.w), w, a6); a7 = fmaf(bfhi(t.w), w, a7);
    }
    // butterfly-sum the 8 groups (lanes xor 8, 16, 32)
    #pragma unroll
    for (int m = 8; m <= 32; m <<= 1) {
        a0 += __shfl_xor(a0, m); a1 += __shfl_xor(a1, m);
        a2 += __shfl_xor(a2, m); a3 += __shfl_xor(a3, m);
        a4 += __shfl_xor(a4, m); a5 += __shfl_xor(a5, m);
        a6 += __shfl_xor(a6, m); a7 += __shfl_xor(a7, m);
    }
    if (grp == 0) {   // lanes 0..7 write the 64-float row (32 B each)
        float dv = dinv[node];
        float s = dv * dv;
        uint4 t = T4[(size_t)node * 8 + fl];
        const float* b = &bias[fl * 8];
        float4 o0, o1;
        o0.x = tanhf(fmaf(bflo(t.x), s, a0) + b[0]);
        o0.y = tanhf(fmaf(bfhi(t.x), s, a1) + b[1]);
        o0.z = tanhf(fmaf(bflo(t.y), s, a2) + b[2]);
        o0.w = tanhf(fmaf(bfhi(t.y), s, a3) + b[3]);
        o1.x = tanhf(fmaf(bflo(t.z), s, a4) + b[4]);
        o1.y = tanhf(fmaf(bfhi(t.z), s, a5) + b[5]);
        o1.z = tanhf(fmaf(bflo(t.w), s, a6) + b[6]);
        o1.w = tanhf(fmaf(bfhi(t.w), s, a7) + b[7]);
        A4[(size_t)node * 16 + fl * 2]     = o0;
        A4[(size_t)node * 16 + fl * 2 + 1] = o1;
    }
}

// ---------------- pooling ----------------
// batch_index is SORTED: gstart via boundary detection (no atomics, no scan).
__global__ void find_bounds(const int* __restrict__ batch, int* __restrict__ gstart) {
    int i = blockIdx.x * 256 + threadIdx.x;
    if (i >= NN) return;
    int cur = batch[i];
    int prev = (i == 0) ? -1 : batch[i - 1];
    for (int g = prev + 1; g <= cur; ++g) gstart[g] = i;   // covers empty graphs
    if (i == NN - 1) {
        for (int g = cur + 1; g <= GG; ++g) gstart[g] = NN;
    }
}

__global__ __launch_bounds__(256) void pool_k(const float* __restrict__ H,
                                              const int* __restrict__ gstart,
                                              float* __restrict__ hidden) {
    __shared__ float smax[4][64], ssum[4][64];
    int g = blockIdx.x;
    int wave = threadIdx.x >> 6, lane = threadIdx.x & 63;
    int beg = gstart[g], end = gstart[g + 1];
    float mx = -FLT_MAX, sm = 0.f;
    for (int i = beg + wave; i < end; i += 4) {
        float v = H[(size_t)i * 64 + lane];
        mx = fmaxf(mx, v);
        sm += v;
    }
    smax[wave][lane] = mx; ssum[wave][lane] = sm;
    __syncthreads();
    if (wave == 0) {
        mx = fmaxf(fmaxf(smax[0][lane], smax[1][lane]), fmaxf(smax[2][lane], smax[3][lane]));
        sm = ssum[0][lane] + ssum[1][lane] + ssum[2][lane] + ssum[3][lane];
        int cnt = end - beg;
        hidden[g * 128 + lane]      = (cnt > 0) ? mx : 0.f;
        hidden[g * 128 + 64 + lane] = sm / fmaxf((float)cnt, 1.f);
    }
}

__global__ void head_k(const float* __restrict__ hidden, const float* __restrict__ Wout,
                       const float* __restrict__ bout, float* __restrict__ out) {
    int g = blockIdx.x, lane = threadIdx.x;   // 64 threads
    float v = hidden[g * 128 + lane] * Wout[lane]
            + hidden[g * 128 + 64 + lane] * Wout[64 + lane];
    #pragma unroll
    for (int off = 32; off; off >>= 1) v += __shfl_down(v, off);
    if (lane == 0) out[g] = 1.f / (1.f + expf(-(v + bout[0])));
}

// ---------------- launch ----------------
extern "C" void kernel_launch(void* const* d_in, const int* in_sizes, int n_in,
                              void* d_out, int out_size, void* d_ws, size_t ws_size,
                              hipStream_t stream) {
    const float* x     = (const float*)d_in[0];
    const int*   ei    = (const int*)d_in[1];
    const int*   src   = ei;
    const int*   dst   = ei + EE;
    const int*   batch = (const int*)d_in[2];
    const float* W0 = (const float*)d_in[4];  const float* b0 = (const float*)d_in[5];
    const float* W1 = (const float*)d_in[6];  const float* b1 = (const float*)d_in[7];
    const float* W2 = (const float*)d_in[8];  const float* b2 = (const float*)d_in[9];
    const float* W3 = (const float*)d_in[10]; const float* b3 = (const float*)d_in[11];
    const float* Wout = (const float*)d_in[12]; const float* bout = (const float*)d_in[13];

    float* out    = (float*)d_out;
    float* hidden = out + GG;     // [G,128] portion of d_out

    char*  w = (char*)d_ws;
    size_t off = 0;
    auto alloc = [&](size_t bytes) -> char* {
        char* p = w + off;
        off = (off + bytes + 255) & ~(size_t)255;
        return p;
    };
    int*   degi    = (int*)  alloc(NN * 4);
    float* dinv    = (float*)alloc(NN * 4);
    int*   row_ptr = (int*)  alloc((NN + 1) * 4);
    int*   cursor  = (int*)  alloc(NN * 4);
    int*   partial = (int*)  alloc(NBLK * 4);
    int2*  cw      = (int2*) alloc((size_t)EE * 8);
    unsigned short* T2 = (unsigned short*)alloc((size_t)NN * 64 * 2);   // bf16
    float* A       = (float*)alloc((size_t)NN * 64 * 4);
    int*   gstart  = (int*)  alloc((GG + 1) * 4);
    (void)ws_size; (void)in_sizes; (void)n_in; (void)out_size;

    // degree + CSR offsets (hierarchical scan)
    init_deg<<<(NN + 255) / 256, 256, 0, stream>>>(degi);
    edge_deg<<<(EE + 255) / 256, 256, 0, stream>>>(dst, degi);
    scan_partial<<<NBLK, 1024, 0, stream>>>(degi, partial);
    scan_offsets<<<1, 128, 0, stream>>>(partial, row_ptr);
    scan_final<<<NBLK, 1024, 0, stream>>>(degi, partial, row_ptr, cursor);
    make_dinv<<<(NN + 255) / 256, 256, 0, stream>>>(degi, dinv);
    fill_csr<<<(EE + 255) / 256, 256, 0, stream>>>(src, dst, dinv, cursor, cw);

    // pooling prep: boundary detection on sorted batch_index
    find_bounds<<<(NN + 255) / 256, 256, 0, stream>>>(batch, gstart);

    // 4 GCN layers (transform(bf16) -> aggregate+bias+tanh)
    const int GB = (NN + 63) / 64;
    gemm_k<FF><<<GB, 256, 0, stream>>>(x, W0, T2);
    agg_k<<<NN / 4, 256, 0, stream>>>((const uint4*)T2, dinv, row_ptr, cw, b0, (float4*)A);
    gemm_k<DD><<<GB, 256, 0, stream>>>(A, W1, T2);
    agg_k<<<NN / 4, 256, 0, stream>>>((const uint4*)T2, dinv, row_ptr, cw, b1, (float4*)A);
    gemm_k<DD><<<GB, 256, 0, stream>>>(A, W2, T2);
    agg_k<<<NN / 4, 256, 0, stream>>>((const uint4*)T2, dinv, row_ptr, cw, b2, (float4*)A);
    gemm_k<DD><<<GB, 256, 0, stream>>>(A, W3, T2);
    agg_k<<<NN / 4, 256, 0, stream>>>((const uint4*)T2, dinv, row_ptr, cw, b3, (float4*)A);

    // pooling + head
    pool_k<<<GG, 256, 0, stream>>>(A, gstart, hidden);
    head_k<<<GG, 64, 0, stream>>>(hidden, Wout, bout, out);
}

// Round 13
// 642.877 us; speedup vs baseline: 2.3291x; 1.0201x over previous
//
#include <hip/hip_runtime.h>
#include <math.h>
#include <float.h>

// Problem constants (fixed by setup_inputs)
#define NN 100000
#define EE 1600000
#define FF 128
#define DD 64
#define GG 512
#define NBLK 98   // ceil(NN/1024)

__device__ __forceinline__ unsigned short f2bf(float f) {
    unsigned u = __float_as_uint(f);
    u = (u + 0x7fff + ((u >> 16) & 1)) >> 16;   // round-to-nearest-even
    return (unsigned short)u;
}
__device__ __forceinline__ float bflo(unsigned u) { return __uint_as_float(u << 16); }
__device__ __forceinline__ float bfhi(unsigned u) { return __uint_as_float(u & 0xffff0000u); }

// ---------------- degree ----------------
__global__ void init_deg(int* degi) {
    int i = blockIdx.x * 256 + threadIdx.x;
    if (i < NN) degi[i] = 1;   // self loop
}

__global__ void edge_deg(const int* __restrict__ dst, int* degi) {
    int e = blockIdx.x * 256 + threadIdx.x;
    if (e < EE) atomicAdd(&degi[dst[e]], 1);
}

__global__ void make_dinv(const int* __restrict__ degi, float* __restrict__ dinv) {
    int i = blockIdx.x * 256 + threadIdx.x;
    if (i < NN) dinv[i] = rsqrtf((float)degi[i]);   // deg >= 1 always
}

// ---------------- hierarchical exclusive scan of indeg = degi-1 ----------------
__global__ void scan_partial(const int* __restrict__ degi, int* __restrict__ partial) {
    __shared__ int red[1024];
    int tid = threadIdx.x;
    int idx = blockIdx.x * 1024 + tid;
    red[tid] = (idx < NN) ? degi[idx] - 1 : 0;
    __syncthreads();
    #pragma unroll
    for (int off = 512; off; off >>= 1) {
        if (tid < off) red[tid] += red[tid + off];
        __syncthreads();
    }
    if (tid == 0) partial[blockIdx.x] = red[0];
}

__global__ void scan_offsets(int* __restrict__ partial, int* __restrict__ row_ptr) {
    __shared__ int tmp[128];
    int tid = threadIdx.x;   // 128 threads
    int v = (tid < NBLK) ? partial[tid] : 0;
    tmp[tid] = v;
    __syncthreads();
    #pragma unroll
    for (int off = 1; off < 128; off <<= 1) {
        int t = (tid >= off) ? tmp[tid - off] : 0;
        __syncthreads();
        tmp[tid] += t;
        __syncthreads();
    }
    if (tid < NBLK) partial[tid] = tmp[tid] - v;     // exclusive block offsets
    if (tid == NBLK - 1) row_ptr[NN] = tmp[tid];     // total == EE
}

__global__ void scan_final(const int* __restrict__ degi, const int* __restrict__ partial,
                           int* __restrict__ row_ptr, int* __restrict__ cursor) {
    __shared__ int tmp[1024];
    int tid = threadIdx.x;
    int idx = blockIdx.x * 1024 + tid;
    int v = (idx < NN) ? degi[idx] - 1 : 0;
    tmp[tid] = v;
    __syncthreads();
    #pragma unroll
    for (int off = 1; off < 1024; off <<= 1) {
        int t = (tid >= off) ? tmp[tid - off] : 0;
        __syncthreads();
        tmp[tid] += t;
        __syncthreads();
    }
    int excl = partial[blockIdx.x] + tmp[tid] - v;
    if (idx < NN) { row_ptr[idx] = excl; cursor[idx] = excl; }
}

// ---------------- CSR fill with precomputed symmetric weights ----------------
__global__ void fill_csr(const int* __restrict__ src, const int* __restrict__ dst,
                         const float* __restrict__ dinv,
                         int* __restrict__ cursor, int2* __restrict__ cw) {
    int e = blockIdx.x * 256 + threadIdx.x;
    if (e < EE) {
        int u = src[e], v = dst[e];
        int pos = atomicAdd(&cursor[v], 1);
        float w = dinv[u] * dinv[v];
        cw[pos] = make_int2(u, __float_as_int(w));
    }
}

// ---------------- dense transform: T = X @ W, bf16 out ----------------
// 64x64 output tile / block, 256 threads, 4x4 register tile per thread.
// K staged in 64-wide slabs (33 KB LDS -> 4 blocks/CU).
template <int K>
__global__ __launch_bounds__(256) void gemm_k(const float* __restrict__ X,
                                              const float* __restrict__ W,
                                              unsigned short* __restrict__ T2) {
    __shared__ float sX[64 * 65];   // [r][k], stride 65 (bank spread + b32 reads)
    __shared__ float sW[64 * 64];   // [k][c], contiguous (b128 reads)
    int tid = threadIdx.x;
    int row0 = blockIdx.x * 64;
    int rows = NN - row0; if (rows > 64) rows = 64;
    int r0 = (tid >> 4) << 2;       // 0,4,..,60
    int c0 = (tid & 15) << 2;       // 0,4,..,60
    float acc[4][4] = {};
    for (int k0 = 0; k0 < K; k0 += 64) {
        // stage W slab (linear, coalesced float4)
        {
            const float4* Wg = (const float4*)(W + (size_t)k0 * 64);
            float4* sW4 = (float4*)sW;
            #pragma unroll
            for (int j = 0; j < 4; ++j) sW4[tid + j * 256] = Wg[tid + j * 256];
        }
        // stage X slab: 64 rows x 64 k (float4 global reads, b32 LDS writes)
        #pragma unroll
        for (int j = 0; j < 4; ++j) {
            int flat = tid + j * 256;          // 0..1023
            int r = flat >> 4, kc = (flat & 15) << 2;
            float4 v = make_float4(0.f, 0.f, 0.f, 0.f);
            if (r < rows) v = *(const float4*)(X + (size_t)(row0 + r) * K + k0 + kc);
            sX[r * 65 + kc]     = v.x;
            sX[r * 65 + kc + 1] = v.y;
            sX[r * 65 + kc + 2] = v.z;
            sX[r * 65 + kc + 3] = v.w;
        }
        __syncthreads();
        #pragma unroll 8
        for (int k = 0; k < 64; ++k) {
            float4 b = *(const float4*)(sW + k * 64 + c0);
            float a0 = sX[r0 * 65 + k];
            float a1 = sX[(r0 + 1) * 65 + k];
            float a2 = sX[(r0 + 2) * 65 + k];
            float a3 = sX[(r0 + 3) * 65 + k];
            acc[0][0] = fmaf(a0, b.x, acc[0][0]); acc[0][1] = fmaf(a0, b.y, acc[0][1]);
            acc[0][2] = fmaf(a0, b.z, acc[0][2]); acc[0][3] = fmaf(a0, b.w, acc[0][3]);
            acc[1][0] = fmaf(a1, b.x, acc[1][0]); acc[1][1] = fmaf(a1, b.y, acc[1][1]);
            acc[1][2] = fmaf(a1, b.z, acc[1][2]); acc[1][3] = fmaf(a1, b.w, acc[1][3]);
            acc[2][0] = fmaf(a2, b.x, acc[2][0]); acc[2][1] = fmaf(a2, b.y, acc[2][1]);
            acc[2][2] = fmaf(a2, b.z, acc[2][2]); acc[2][3] = fmaf(a2, b.w, acc[2][3]);
            acc[3][0] = fmaf(a3, b.x, acc[3][0]); acc[3][1] = fmaf(a3, b.y, acc[3][1]);
            acc[3][2] = fmaf(a3, b.z, acc[3][2]); acc[3][3] = fmaf(a3, b.w, acc[3][3]);
        }
        __syncthreads();
    }
    #pragma unroll
    for (int i = 0; i < 4; ++i) {
        int r = row0 + r0 + i;
        if (r < NN) {
            ushort4 o;
            o.x = f2bf(acc[i][0]); o.y = f2bf(acc[i][1]);
            o.z = f2bf(acc[i][2]); o.w = f2bf(acc[i][3]);
            *(ushort4*)(T2 + (size_t)r * 64 + c0) = o;
        }
    }
}

// ---------------- aggregation (bf16 gather, 2 chains in flight per lane) ----------------
// One wave per node. 8 groups of 8 lanes; group g handles edges beg+grp, beg+grp+8, ...
// Unrolled x2: two independent cw->T4 gather chains per lane hide latency.
__global__ __launch_bounds__(256) void agg_k(const uint4* __restrict__ T4,   // [N*8] uint4
                                             const float* __restrict__ dinv,
                                             const int* __restrict__ row_ptr,
                                             const int2* __restrict__ cw,
                                             const float* __restrict__ bias,
                                             float4* __restrict__ A4) {
    int node = blockIdx.x * 4 + (threadIdx.x >> 6);
    int lane = threadIdx.x & 63;
    int grp  = lane >> 3;      // 0..7 : edge slot
    int fl   = lane & 7;       // which 8-feature chunk
    int beg = row_ptr[node], end = row_ptr[node + 1];
    float a0=0,a1=0,a2=0,a3=0,a4=0,a5=0,a6=0,a7=0;
    int j = beg + grp;
    for (; j + 8 < end; j += 16) {   // two edges per iteration
        int2 c1 = cw[j];
        int2 c2 = cw[j + 8];
        uint4 t1 = T4[(size_t)c1.x * 8 + fl];
        uint4 t2 = T4[(size_t)c2.x * 8 + fl];
        float w1 = __int_as_float(c1.y);
        float w2 = __int_as_float(c2.y);
        a0 = fmaf(bflo(t1.x), w1, a0); a1 = fmaf(bfhi(t1.x), w1, a1);
        a2 = fmaf(bflo(t1.y), w1, a2); a3 = fmaf(bfhi(t1.y), w1, a3);
        a4 = fmaf(bflo(t1.z), w1, a4); a5 = fmaf(bfhi(t1.z), w1, a5);
        a6 = fmaf(bflo(t1.w), w1, a6); a7 = fmaf(bfhi(t1.w), w1, a7);
        a0 = fmaf(bflo(t2.x), w2, a0); a1 = fmaf(bfhi(t2.x), w2, a1);
        a2 = fmaf(bflo(t2.y), w2, a2); a3 = fmaf(bfhi(t2.y), w2, a3);
        a4 = fmaf(bflo(t2.z), w2, a4); a5 = fmaf(bfhi(t2.z), w2, a5);
        a6 = fmaf(bflo(t2.w), w2, a6); a7 = fmaf(bfhi(t2.w), w2, a7);
    }
    if (j < end) {
        int2 c = cw[j];
        float w = __int_as_float(c.y);
        uint4 t = T4[(size_t)c.x * 8 + fl];
        a0 = fmaf(bflo(t.x), w, a0); a1 = fmaf(bfhi(t.x), w, a1);
        a2 = fmaf(bflo(t.y), w, a2); a3 = fmaf(bfhi(t.y), w, a3);
        a4 = fmaf(bflo(t.z), w, a4); a5 = fmaf(bfhi(t.z), w, a5);
        a6 = fmaf(bflo(t.w), w, a6); a7 = fmaf(bfhi(t.w), w, a7);
    }
    // butterfly-sum the 8 groups (lanes xor 8, 16, 32)
    #pragma unroll
    for (int m = 8; m <= 32; m <<= 1) {
        a0 += __shfl_xor(a0, m); a1 += __shfl_xor(a1, m);
        a2 += __shfl_xor(a2, m); a3 += __shfl_xor(a3, m);
        a4 += __shfl_xor(a4, m); a5 += __shfl_xor(a5, m);
        a6 += __shfl_xor(a6, m); a7 += __shfl_xor(a7, m);
    }
    if (grp == 0) {   // lanes 0..7 write the 64-float row (32 B each)
        float dv = dinv[node];
        float s = dv * dv;
        uint4 t = T4[(size_t)node * 8 + fl];
        const float* b = &bias[fl * 8];
        float4 o0, o1;
        o0.x = tanhf(fmaf(bflo(t.x), s, a0) + b[0]);
        o0.y = tanhf(fmaf(bfhi(t.x), s, a1) + b[1]);
        o0.z = tanhf(fmaf(bflo(t.y), s, a2) + b[2]);
        o0.w = tanhf(fmaf(bfhi(t.y), s, a3) + b[3]);
        o1.x = tanhf(fmaf(bflo(t.z), s, a4) + b[4]);
        o1.y = tanhf(fmaf(bfhi(t.z), s, a5) + b[5]);
        o1.z = tanhf(fmaf(bflo(t.w), s, a6) + b[6]);
        o1.w = tanhf(fmaf(bfhi(t.w), s, a7) + b[7]);
        A4[(size_t)node * 16 + fl * 2]     = o0;
        A4[(size_t)node * 16 + fl * 2 + 1] = o1;
    }
}

// ---------------- pooling ----------------
// batch_index is SORTED: gstart via boundary detection (no atomics, no scan).
__global__ void find_bounds(const int* __restrict__ batch, int* __restrict__ gstart) {
    int i = blockIdx.x * 256 + threadIdx.x;
    if (i >= NN) return;
    int cur = batch[i];
    int prev = (i == 0) ? -1 : batch[i - 1];
    for (int g = prev + 1; g <= cur; ++g) gstart[g] = i;   // covers empty graphs
    if (i == NN - 1) {
        for (int g = cur + 1; g <= GG; ++g) gstart[g] = NN;
    }
}

__global__ __launch_bounds__(256) void pool_k(const float* __restrict__ H,
                                              const int* __restrict__ gstart,
                                              float* __restrict__ hidden) {
    __shared__ float smax[4][64], ssum[4][64];
    int g = blockIdx.x;
    int wave = threadIdx.x >> 6, lane = threadIdx.x & 63;
    int beg = gstart[g], end = gstart[g + 1];
    float mx = -FLT_MAX, sm = 0.f;
    for (int i = beg + wave; i < end; i += 4) {
        float v = H[(size_t)i * 64 + lane];
        mx = fmaxf(mx, v);
        sm += v;
    }
    smax[wave][lane] = mx; ssum[wave][lane] = sm;
    __syncthreads();
    if (wave == 0) {
        mx = fmaxf(fmaxf(smax[0][lane], smax[1][lane]), fmaxf(smax[2][lane], smax[3][lane]));
        sm = ssum[0][lane] + ssum[1][lane] + ssum[2][lane] + ssum[3][lane];
        int cnt = end - beg;
        hidden[g * 128 + lane]      = (cnt > 0) ? mx : 0.f;
        hidden[g * 128 + 64 + lane] = sm / fmaxf((float)cnt, 1.f);
    }
}

__global__ void head_k(const float* __restrict__ hidden, const float* __restrict__ Wout,
                       const float* __restrict__ bout, float* __restrict__ out) {
    int g = blockIdx.x, lane = threadIdx.x;   // 64 threads
    float v = hidden[g * 128 + lane] * Wout[lane]
            + hidden[g * 128 + 64 + lane] * Wout[64 + lane];
    #pragma unroll
    for (int off = 32; off; off >>= 1) v += __shfl_down(v, off);
    if (lane == 0) out[g] = 1.f / (1.f + expf(-(v + bout[0])));
}

// ---------------- launch ----------------
extern "C" void kernel_launch(void* const* d_in, const int* in_sizes, int n_in,
                              void* d_out, int out_size, void* d_ws, size_t ws_size,
                              hipStream_t stream) {
    const float* x     = (const float*)d_in[0];
    const int*   ei    = (const int*)d_in[1];
    const int*   src   = ei;
    const int*   dst   = ei + EE;
    const int*   batch = (const int*)d_in[2];
    const float* W0 = (const float*)d_in[4];  const float* b0 = (const float*)d_in[5];
    const float* W1 = (const float*)d_in[6];  const float* b1 = (const float*)d_in[7];
    const float* W2 = (const float*)d_in[8];  const float* b2 = (const float*)d_in[9];
    const float* W3 = (const float*)d_in[10]; const float* b3 = (const float*)d_in[11];
    const float* Wout = (const float*)d_in[12]; const float* bout = (const float*)d_in[13];

    float* out    = (float*)d_out;
    float* hidden = out + GG;     // [G,128] portion of d_out

    char*  w = (char*)d_ws;
    size_t off = 0;
    auto alloc = [&](size_t bytes) -> char* {
        char* p = w + off;
        off = (off + bytes + 255) & ~(size_t)255;
        return p;
    };
    int*   degi    = (int*)  alloc(NN * 4);
    float* dinv    = (float*)alloc(NN * 4);
    int*   row_ptr = (int*)  alloc((NN + 1) * 4);
    int*   cursor  = (int*)  alloc(NN * 4);
    int*   partial = (int*)  alloc(NBLK * 4);
    int2*  cw      = (int2*) alloc((size_t)EE * 8);
    unsigned short* T2 = (unsigned short*)alloc((size_t)NN * 64 * 2);   // bf16
    float* A       = (float*)alloc((size_t)NN * 64 * 4);
    int*   gstart  = (int*)  alloc((GG + 1) * 4);
    (void)ws_size; (void)in_sizes; (void)n_in; (void)out_size;

    // degree + CSR offsets (hierarchical scan)
    init_deg<<<(NN + 255) / 256, 256, 0, stream>>>(degi);
    edge_deg<<<(EE + 255) / 256, 256, 0, stream>>>(dst, degi);
    scan_partial<<<NBLK, 1024, 0, stream>>>(degi, partial);
    scan_offsets<<<1, 128, 0, stream>>>(partial, row_ptr);
    scan_final<<<NBLK, 1024, 0, stream>>>(degi, partial, row_ptr, cursor);
    make_dinv<<<(NN + 255) / 256, 256, 0, stream>>>(degi, dinv);
    fill_csr<<<(EE + 255) / 256, 256, 0, stream>>>(src, dst, dinv, cursor, cw);

    // pooling prep: boundary detection on sorted batch_index
    find_bounds<<<(NN + 255) / 256, 256, 0, stream>>>(batch, gstart);

    // 4 GCN layers (transform(bf16) -> aggregate+bias+tanh)
    const int GB = (NN + 63) / 64;
    gemm_k<FF><<<GB, 256, 0, stream>>>(x, W0, T2);
    agg_k<<<NN / 4, 256, 0, stream>>>((const uint4*)T2, dinv, row_ptr, cw, b0, (float4*)A);
    gemm_k<DD><<<GB, 256, 0, stream>>>(A, W1, T2);
    agg_k<<<NN / 4, 256, 0, stream>>>((const uint4*)T2, dinv, row_ptr, cw, b1, (float4*)A);
    gemm_k<DD><<<GB, 256, 0, stream>>>(A, W2, T2);
    agg_k<<<NN / 4, 256, 0, stream>>>((const uint4*)T2, dinv, row_ptr, cw, b2, (float4*)A);
    gemm_k<DD><<<GB, 256, 0, stream>>>(A, W3, T2);
    agg_k<<<NN / 4, 256, 0, stream>>>((const uint4*)T2, dinv, row_ptr, cw, b3, (float4*)A);

    // pooling + head
    pool_k<<<GG, 256, 0, stream>>>(A, gstart, hidden);
    head_k<<<GG, 64, 0, stream>>>(hidden, Wout, bout, out);
}